// Round 5
// baseline (332.129 us; speedup 1.0000x reference)
//
#include <hip/hip_runtime.h>
#include <hip/hip_bf16.h>

typedef __bf16 bf16x8 __attribute__((ext_vector_type(8)));
typedef unsigned short u16x8 __attribute__((ext_vector_type(8)));
typedef float f32x4 __attribute__((ext_vector_type(4)));
typedef float f32x16 __attribute__((ext_vector_type(16)));
typedef __hip_bfloat16 bf16;

// async 16B global -> LDS (lds dest = wave-uniform base + lane*16)
#define GLOAD_LDS16(g, l)                                               \
  __builtin_amdgcn_global_load_lds(                                     \
      (__attribute__((address_space(1))) void*)(void*)(g),              \
      (__attribute__((address_space(3))) void*)(void*)(l), 16, 0, 0)

// ---------------------------------------------------------------------------
// all five fp32 -> bf16 converts in one kernel
// ---------------------------------------------------------------------------
__global__ __launch_bounds__(256) void cvt_all(
    const float4* __restrict__ x,  const float4* __restrict__ qw,
    const float4* __restrict__ kw, const float4* __restrict__ vw,
    const float4* __restrict__ ow,
    ushort4* __restrict__ xb,  ushort4* __restrict__ qwb,
    ushort4* __restrict__ kwb, ushort4* __restrict__ vwb,
    ushort4* __restrict__ owb)
{
  const int i = blockIdx.x * 256 + threadIdx.x;
  const float4* s; ushort4* d; int off;
  if      (i < 2097152) { s = x;  d = xb;  off = i; }
  else if (i < 3145728) { s = qw; d = qwb; off = i - 2097152; }
  else if (i < 3407872) { s = kw; d = kwb; off = i - 3145728; }
  else if (i < 3670016) { s = vw; d = vwb; off = i - 3407872; }
  else                  { s = ow; d = owb; off = i - 3670016; }
  float4 v = s[off];
  bf16 b0 = __float2bfloat16(v.x), b1 = __float2bfloat16(v.y);
  bf16 b2 = __float2bfloat16(v.z), b3 = __float2bfloat16(v.w);
  ushort4 o;
  o.x = *(unsigned short*)&b0; o.y = *(unsigned short*)&b1;
  o.z = *(unsigned short*)&b2; o.w = *(unsigned short*)&b3;
  d[off] = o;
}

// ---------------------------------------------------------------------------
// GEMM: C[M,N] = A[M,K] * W[N,K]^T   bf16 in, fp32 accum, OutT out
// ---------------------------------------------------------------------------
__device__ __forceinline__ void store_out(bf16* p, float v)  { *p = __float2bfloat16(v); }
__device__ __forceinline__ void store_out(float* p, float v) { *p = v; }

template <typename OutT>
__device__ __forceinline__ void gemm_tile_body(
    const bf16* __restrict__ A, const bf16* __restrict__ W, OutT* __restrict__ C,
    int bm, int bn, int N, int K, bf16* As, bf16* Ws)
{
  const int tid  = threadIdx.x;
  const int lane = tid & 63;
  const int wave = tid >> 6;
  const int wm = (wave >> 1) * 64;
  const int wn = (wave & 1) * 64;
  const int mfrag = lane & 15;
  const int kfrag = (lane >> 4) * 8;

  f32x4 acc[4][4] = {};

  for (int k0 = 0; k0 < K; k0 += 32) {
#pragma unroll
    for (int r = 0; r < 2; ++r) {
      const int off  = r * 4096 + wave * 1024 + lane * 16;
      const int row  = off >> 6;
      const int colb = off & 63;
      const char* ga = (const char*)A + ((size_t)(bm + row) * K + k0) * 2 + colb;
      GLOAD_LDS16(ga, (char*)As + r * 4096 + wave * 1024);
      const char* gw = (const char*)W + ((size_t)(bn + row) * K + k0) * 2 + colb;
      GLOAD_LDS16(gw, (char*)Ws + r * 4096 + wave * 1024);
    }
    __syncthreads();

    bf16x8 af[4], wf[4];
#pragma unroll
    for (int i = 0; i < 4; ++i)
      af[i] = *(const bf16x8*)(As + (wm + i * 16 + mfrag) * 32 + kfrag);
#pragma unroll
    for (int j = 0; j < 4; ++j)
      wf[j] = *(const bf16x8*)(Ws + (wn + j * 16 + mfrag) * 32 + kfrag);
#pragma unroll
    for (int i = 0; i < 4; ++i)
#pragma unroll
      for (int j = 0; j < 4; ++j)
        acc[i][j] = __builtin_amdgcn_mfma_f32_16x16x32_bf16(af[i], wf[j], acc[i][j], 0, 0, 0);
    __syncthreads();
  }

  const int rq = (lane >> 4) * 4;
#pragma unroll
  for (int i = 0; i < 4; ++i)
#pragma unroll
    for (int j = 0; j < 4; ++j)
#pragma unroll
      for (int r = 0; r < 4; ++r) {
        const int row = bm + wm + i * 16 + rq + r;
        const int col = bn + wn + j * 16 + mfrag;
        store_out(&C[(size_t)row * N + col], acc[i][j][r]);
      }
}

__global__ __launch_bounds__(256) void gemm_bt_f32out(
    const bf16* __restrict__ A, const bf16* __restrict__ W, float* __restrict__ C,
    int N, int K)
{
  __shared__ bf16 As[128 * 32];
  __shared__ bf16 Ws[128 * 32];
  gemm_tile_body<float>(A, W, C, blockIdx.y * 128, blockIdx.x * 128, N, K, As, Ws);
}

__global__ __launch_bounds__(256) void gemm_qkv(
    const bf16* __restrict__ X, const bf16* __restrict__ Wq,
    const bf16* __restrict__ Wk, const bf16* __restrict__ Wv,
    bf16* __restrict__ Qo, bf16* __restrict__ Ko, bf16* __restrict__ Vo, int K)
{
  __shared__ bf16 As[128 * 32];
  __shared__ bf16 Ws[128 * 32];
  const int bx = blockIdx.x;
  const bf16* W; bf16* C; int N, bn;
  if (bx < 16)      { W = Wq; C = Qo; N = 2048; bn = bx * 128; }
  else if (bx < 20) { W = Wk; C = Ko; N = 512;  bn = (bx - 16) * 128; }
  else              { W = Wv; C = Vo; N = 512;  bn = (bx - 20) * 128; }
  gemm_tile_body<bf16>(X, W, C, blockIdx.y * 128, bn, N, K, As, Ws);
}

// ---------------------------------------------------------------------------
// post-QKV fixups in one kernel: rope(Q), rope(K), transpose(V)
// ---------------------------------------------------------------------------
__device__ __forceinline__ void rope_row(
    bf16* __restrict__ buf, const float* __restrict__ gain,
    int nh, float scale, int row)
{
  const int j = threadIdx.x & 63;
  const int bt = row / nh;
  const int h  = row - bt * nh;
  const int t  = bt & 2047;  // T = 2048
  bf16* p = buf + (size_t)bt * (nh * 128) + h * 128;

  float x1 = __bfloat162float(p[j]);
  float x2 = __bfloat162float(p[j + 64]);
  float ss = x1 * x1 + x2 * x2;
#pragma unroll
  for (int off = 32; off > 0; off >>= 1) ss += __shfl_xor(ss, off, 64);
  const float rinv = rsqrtf(ss * (1.0f / 128.0f) + 1.1920928955078125e-07f);
  const float g = gain ? gain[h] : 1.0f;
  const float s = rinv * g * scale;

  // base = 10000 * 2^(128/126) (T=2048 > TRAIN=1024); log2(base) = 14.3035853954
  const float inv_freq = exp2f(-(float)j * (14.3035853954f / 64.0f));
  const float fr = (float)t * inv_freq;
  const float cs = cosf(fr), sn = sinf(fr);
  p[j]      = __float2bfloat16(s * (x1 * cs + x2 * sn));
  p[j + 64] = __float2bfloat16(s * (x2 * cs - x1 * sn));
}

__global__ __launch_bounds__(256) void postqkv(
    bf16* __restrict__ qb, bf16* __restrict__ kb,
    const unsigned short* __restrict__ vb, unsigned short* __restrict__ vtb,
    const float* __restrict__ gain)
{
  const int bx = blockIdx.x;
  if (bx < 16384) {
    rope_row(qb, gain, 16, 0.08838834764831845f, bx * 4 + (threadIdx.x >> 6));
  } else if (bx < 20480) {
    rope_row(kb, nullptr, 4, 1.0f, (bx - 16384) * 4 + (threadIdx.x >> 6));
  } else {
    const int idx = (bx - 20480) * 256 + threadIdx.x;  // 256K threads
    const int t  = idx & 4095;
    const int dc = idx >> 12;                          // [0,64)
    u16x8 v = *(const u16x8*)(vb + (size_t)t * 512 + dc * 8);
#pragma unroll
    for (int j = 0; j < 8; ++j)
      vtb[(size_t)(dc * 8 + j) * 4096 + t] = v[j];
  }
}

// ---------------------------------------------------------------------------
// MFMA flash attention v4: 32x32x16 MFMA with TWO GQA heads stacked in the
// A-operand (rows 0-15 = head hA, 16-31 = head hA+1) -- halves per-wave LDS
// K/V fragment traffic, which the R4 counters showed to be the convoy
// bottleneck. Fixed softmax max (exp(S-14), Cauchy-Schwarz bound), per-lane
// l accumulation, single barrier/tile, K+V double-buffered via
// global_load_lds. Block = 4 waves x (2 heads x 16q) = 2 heads x 64 q-rows;
// paired q-tiles (31-p, p) -> 256 uniform blocks of 33 tiles, 1 block/CU,
// LDS 80 KB.
// ---------------------------------------------------------------------------
__global__ __launch_bounds__(256, 1) void flash_attn(
    const bf16* __restrict__ Q, const bf16* __restrict__ Kg,
    const bf16* __restrict__ Vtg, bf16* __restrict__ Y)
{
  __shared__ bf16 Ks[2][64 * 128];  // [key][d], XOR-swizzled 16B chunks
  __shared__ bf16 Vs[2][128 * 64];  // [d][key], swizzled
  __shared__ bf16 Ps[4][32 * 64];   // per-wave P [m=2head*16q][key], swizzled

  const int tid  = threadIdx.x, lane = tid & 63, w = tid >> 6;
  const int p    = blockIdx.x & 15;
  const int hp   = (blockIdx.x >> 4) & 1;
  const int kvh  = (blockIdx.x >> 5) & 3;
  const int b    = blockIdx.x >> 7;
  const int hA   = kvh * 4 + hp * 2;
  const int l31  = lane & 31;
  const int half = lane >> 5;
  const int l7   = lane & 7;

  auto stage_k = [&](int kt, int s) {
#pragma unroll
    for (int g = 0; g < 4; ++g) {
      const int o = g * 4096 + w * 1024 + lane * 16;  // byte offset, 256 B rows
      const int r = o >> 8, c = (o >> 4) & 15;
      const int cs = (c & 8) | ((c ^ (r & 7)) & 7);
      const bf16* src = Kg + ((size_t)(b * 2048 + kt * 64 + r)) * 512 + kvh * 128 + cs * 8;
      GLOAD_LDS16(src, (char*)&Ks[s][0] + g * 4096 + w * 1024);
    }
  };
  auto stage_v = [&](int kt, int s) {
#pragma unroll
    for (int g = 0; g < 4; ++g) {
      const int o = g * 4096 + w * 1024 + lane * 16;  // byte offset, 128 B rows
      const int r = o >> 7, c = (o >> 4) & 7;
      const int cs = (c ^ (r & 7)) & 7;
      const bf16* src = Vtg + ((size_t)(kvh * 128 + r)) * 4096 + b * 2048 + kt * 64 + cs * 8;
      GLOAD_LDS16(src, (char*)&Vs[s][0] + g * 4096 + w * 1024);
    }
  };

  stage_k(0, 0);
  stage_v(0, 0);
  int sb = 0;
  bf16* psw = &Ps[w][0];

  for (int phase = 0; phase < 2; ++phase) {
    const int qt = phase ? p : 31 - p;

    // Q A-frags: m = l31 -> head hA + (m>>4), q-row = qt*64 + w*16 + (m&15)
    bf16x8 qf[8];
    {
      const bf16* qrow = Q + ((size_t)(b * 2048 + qt * 64 + w * 16 + (l31 & 15))) * 2048
                           + (hA + (l31 >> 4)) * 128 + half * 8;
#pragma unroll
      for (int c = 0; c < 8; ++c) qf[c] = *(const bf16x8*)(qrow + c * 16);
    }

    f32x16 oacc[4] = {};
    float l_lane[16];
#pragma unroll
    for (int r = 0; r < 16; ++r) l_lane[r] = 0.f;
    const int qb0 = qt * 64 + w * 16;

    for (int kt = 0; kt <= qt; ++kt) {
      __syncthreads();  // prefetch into [sb] drained; [sb^1] free for overwrite
      const bool last = (phase == 1) && (kt == qt);
      if (!last) {
        const int nk = kt < qt ? kt + 1 : 0;
        stage_k(nk, sb ^ 1);
        stage_v(nk, sb ^ 1);
      }

      // ---- S = Q K^T : 2 key-blocks of 32, contraction 128 in 8 k-steps
      f32x16 sc[2] = {};
#pragma unroll
      for (int kb = 0; kb < 2; ++kb) {
        const bf16* krow = &Ks[sb][0] + (kb * 32 + l31) * 128;
#pragma unroll
        for (int c = 0; c < 8; ++c) {
          const int G = c * 2 + half;
          const int cs = (G & 8) | ((G ^ l7) & 7);
          bf16x8 kf = *(const bf16x8*)(krow + cs * 8);
          sc[kb] = __builtin_amdgcn_mfma_f32_32x32x16_bf16(qf[c], kf, sc[kb], 0, 0, 0);
        }
      }

      // ---- causal mask (diagonal tile only); head-independent (row&15 = q)
      if (kt == qt) {
#pragma unroll
        for (int kb = 0; kb < 2; ++kb) {
          const int key = kt * 64 + kb * 32 + l31;
#pragma unroll
          for (int r = 0; r < 16; ++r) {
            const int row = (r & 3) + 8 * (r >> 2) + 4 * half;
            if (key > qb0 + (row & 15)) sc[kb][r] = -1e30f;
          }
        }
      }

      // ---- P = exp(S - 14); per-lane l accumulation; P -> own-wave LDS
#pragma unroll
      for (int kb = 0; kb < 2; ++kb)
#pragma unroll
        for (int r = 0; r < 16; ++r) {
          const float pv = __expf(sc[kb][r] - 14.0f);
          l_lane[r] += pv;
          const int row  = (r & 3) + 8 * (r >> 2) + 4 * half;
          const int key  = kb * 32 + l31;
          const int slot = ((key >> 3) ^ (row & 7)) & 7;
          psw[row * 64 + slot * 8 + (key & 7)] = __float2bfloat16(pv);
        }

      // ---- O += P V : A = P [m=32][k=64], B = Vs rows [d][key]
#pragma unroll
      for (int c2 = 0; c2 < 4; ++c2) {
        const int sl = ((c2 * 2 + half) ^ l7) & 7;
        bf16x8 pf = *(const bf16x8*)(psw + l31 * 64 + sl * 8);
#pragma unroll
        for (int db = 0; db < 4; ++db) {
          bf16x8 vf = *(const bf16x8*)(&Vs[sb][0] + (db * 32 + l31) * 64 + sl * 8);
          oacc[db] = __builtin_amdgcn_mfma_f32_32x32x16_bf16(pf, vf, oacc[db], 0, 0, 0);
        }
      }
      sb ^= 1;
    }

    // ---- epilogue: reduce l over the 32 col-lanes of each row, store
#pragma unroll
    for (int r = 0; r < 16; ++r) {
      float l = l_lane[r];
      l += __shfl_xor(l, 1, 64);
      l += __shfl_xor(l, 2, 64);
      l += __shfl_xor(l, 4, 64);
      l += __shfl_xor(l, 8, 64);
      l += __shfl_xor(l, 16, 64);
      const float linv = 1.0f / l;
      const int row = (r & 3) + 8 * (r >> 2) + 4 * half;
      bf16* yp = Y + ((size_t)(b * 2048 + qb0 + (row & 15))) * 2048
                   + (hA + (row >> 4)) * 128 + l31;
#pragma unroll
      for (int db = 0; db < 4; ++db)
        yp[db * 32] = __float2bfloat16(oacc[db][r] * linv);
    }
  }
}

// ---------------------------------------------------------------------------
extern "C" void kernel_launch(void* const* d_in, const int* in_sizes, int n_in,
                              void* d_out, int out_size, void* d_ws, size_t ws_size,
                              hipStream_t stream)
{
  const float* x      = (const float*)d_in[0];
  const float* q_w    = (const float*)d_in[1];
  const float* k_w    = (const float*)d_in[2];
  const float* v_w    = (const float*)d_in[3];
  const float* o_w    = (const float*)d_in[4];
  const float* q_gain = (const float*)d_in[5];
  float* out = (float*)d_out;

  char* ws = (char*)d_ws;
  bf16* xb  = (bf16*)(ws);                   // 4096x2048 = 16 MB
  bf16* yb  = (bf16*)(ws);                   // alias of xb
  bf16* qwb = (bf16*)(ws + (16u << 20));     // 2048x2048 = 8 MB
  bf16* vtb = (bf16*)(ws + (16u << 20));     // 512x4096  = 4 MB (after qwb dead)
  bf16* owb = (bf16*)(ws + (24u << 20));     // 2048x2048 = 8 MB
  bf16* kwb = (bf16*)(ws + (32u << 20));     // 512x2048  = 2 MB
  bf16* vwb = (bf16*)(ws + (34u << 20));     // 512x2048  = 2 MB
  bf16* qb  = (bf16*)(ws + (36u << 20));     // 4096x2048 = 16 MB
  bf16* kb  = (bf16*)(ws + (52u << 20));     // 4096x512  = 4 MB
  bf16* vb  = (bf16*)(ws + (56u << 20));     // 4096x512  = 4 MB  (total 60 MB)

  const dim3 blk(256);
  cvt_all<<<dim3(18432), blk, 0, stream>>>(
      (const float4*)x, (const float4*)q_w, (const float4*)k_w,
      (const float4*)v_w, (const float4*)o_w,
      (ushort4*)xb, (ushort4*)qwb, (ushort4*)kwb, (ushort4*)vwb, (ushort4*)owb);

  gemm_qkv<<<dim3(24, 32), blk, 0, stream>>>(xb, qwb, kwb, vwb, qb, kb, vb, 2048);

  postqkv<<<dim3(21504), blk, 0, stream>>>(
      qb, kb, (const unsigned short*)vb, (unsigned short*)vtb, q_gain);

  flash_attn<<<dim3(256), blk, 0, stream>>>(qb, kb, vtb, yb);

  gemm_bt_f32out<<<dim3(16, 32), blk, 0, stream>>>(yb, owb, out, 2048, 2048);
}